// Round 22
// baseline (1556.232 us; speedup 1.0000x reference)
//
#include <hip/hip_runtime.h>

#define HID 256
typedef unsigned short bfb;  // f16 storage (raw bits)
typedef _Float16 f16x8_t __attribute__((ext_vector_type(8)));
typedef __attribute__((ext_vector_type(4))) float f32x4_t;

// ---------- f16 bit helpers (storage-only; math in fp32) ----------
__device__ inline float bfb2f(bfb u) {
  _Float16 h;
  __builtin_memcpy(&h, &u, 2);
  return (float)h;
}
__device__ inline bfb f2bfb(float f) {
  _Float16 h = (_Float16)f;
  bfb u;
  __builtin_memcpy(&u, &h, 2);
  return u;
}
__device__ inline float ldf(const bfb* p, size_t i) { return bfb2f(p[i]); }
__device__ inline void stf(bfb* p, size_t i, float v) { p[i] = f2bfb(v); }

__device__ inline void gld16(const void* g, void* l) {
  __builtin_amdgcn_global_load_lds(
      (const __attribute__((address_space(1))) void*)g,
      (__attribute__((address_space(3))) void*)l, 16, 0, 0);
}
__device__ inline f32x4_t mfma16(f16x8_t a, f16x8_t b, f32x4_t c) {
  return __builtin_amdgcn_mfma_f32_16x16x32_f16(a, b, c, 0, 0, 0);
}

// ---------------- weight prep: MFMA-fragment-packed f16 ----------------
// dst[e], e = ((ntile*8 + g)*64 + lane)*8 + r  holds W[k][n] with
// n = ntile*16 + (lane&15), k = g*32 + ((lane>>4)&3)*8 + r.
__global__ __launch_bounds__(256) void k_prep_w(
    const float* __restrict__ w1, const float* __restrict__ w2,
    bfb* __restrict__ wbuf, int n_layers) {
  int t = blockIdx.x * 256 + threadIdx.x;
  int total = n_layers * 2 * 65536;
  if (t >= total) return;
  int l = t / 131072;
  int rem = t - l * 131072;
  int which = rem >> 16;
  int e = rem & 65535;
  int r = e & 7;
  int lane = (e >> 3) & 63;
  int g = (e >> 9) & 7;
  int nt = e >> 12;
  int n = nt * 16 + (lane & 15);
  int k = g * 32 + ((lane >> 4) & 3) * 8 + r;
  const float* src = (which ? w2 : w1) + (size_t)l * 65536;
  bfb* dst = wbuf + (size_t)l * 131072 + (size_t)which * 65536;
  dst[e] = f2bfb(src[k * 256 + n]);
}

// ---------------- input projection ----------------
__global__ __launch_bounds__(256) void k_input_proj(
    const float* __restrict__ x, const float* __restrict__ W,
    const float* __restrict__ bias, bfb* __restrict__ z, int n_nodes) {
  __shared__ float sW[14 * HID];
  __shared__ float sx[64 * 14];
  for (int i = threadIdx.x; i < 14 * HID; i += blockDim.x) sW[i] = W[i];
  int c = threadIdx.x;
  float b = bias[c];
  int n0 = blockIdx.x * 64;
  int nmax = min(n0 + 64, n_nodes);
  int cnt = (nmax - n0) * 14;
  for (int i = threadIdx.x; i < cnt; i += blockDim.x) sx[i] = x[(size_t)n0 * 14 + i];
  __syncthreads();
  for (int n = n0; n < nmax; n++) {
    const float* xr = &sx[(n - n0) * 14];
    float acc = b;
#pragma unroll
    for (int k = 0; k < 14; k++) acc = fmaf(xr[k], sW[k * HID + c], acc);
    stf(z, (size_t)n * HID + c, acc);
  }
}

// ---------------- CSR build ----------------
__global__ __launch_bounds__(256) void k_hist(const int* __restrict__ dsts,
                                              int* deg, int ne) {
  int e = blockIdx.x * 256 + threadIdx.x;
  if (e < ne) atomicAdd(&deg[dsts[e]], 1);
}

__global__ __launch_bounds__(256) void k_scan1(const int* __restrict__ deg,
                                               int* bsum, int n) {
  __shared__ int sd[256];
  int i0 = blockIdx.x * 1024 + threadIdx.x * 4;
  int s = 0;
#pragma unroll
  for (int j = 0; j < 4; j++) {
    int i = i0 + j;
    if (i < n) s += deg[i];
  }
  sd[threadIdx.x] = s;
  __syncthreads();
  for (int off = 128; off > 0; off >>= 1) {
    if (threadIdx.x < off) sd[threadIdx.x] += sd[threadIdx.x + off];
    __syncthreads();
  }
  if (threadIdx.x == 0) bsum[blockIdx.x] = sd[0];
}

__global__ __launch_bounds__(256) void k_scan2(int* bsum, int nb) {
  __shared__ int sd[256];
  __shared__ int stot;
  int tid = threadIdx.x;
  int carry = 0;
  for (int base = 0; base < nb; base += 256) {
    int v = (base + tid < nb) ? bsum[base + tid] : 0;
    sd[tid] = v;
    __syncthreads();
    for (int off = 1; off < 256; off <<= 1) {
      int t = (tid >= off) ? sd[tid - off] : 0;
      __syncthreads();
      sd[tid] += t;
      __syncthreads();
    }
    int incl = sd[tid];
    if (base + tid < nb) bsum[base + tid] = carry + incl - v;
    if (tid == 255) stot = incl;
    __syncthreads();
    carry += stot;
    __syncthreads();
  }
}

__global__ __launch_bounds__(256) void k_scan3(const int* __restrict__ deg,
                                               const int* __restrict__ bsum,
                                               int* row_start, int* cursor, int n) {
  __shared__ int sd[256];
  int tid = threadIdx.x;
  int i0 = blockIdx.x * 1024 + tid * 4;
  int d[4];
  int s = 0;
#pragma unroll
  for (int j = 0; j < 4; j++) {
    int i = i0 + j;
    d[j] = (i < n) ? deg[i] : 0;
    s += d[j];
  }
  sd[tid] = s;
  __syncthreads();
  for (int off = 1; off < 256; off <<= 1) {
    int t = (tid >= off) ? sd[tid - off] : 0;
    __syncthreads();
    sd[tid] += t;
    __syncthreads();
  }
  int excl = sd[tid] - s + bsum[blockIdx.x];
#pragma unroll
  for (int j = 0; j < 4; j++) {
    int i = i0 + j;
    if (i < n) {
      row_start[i] = excl;
      cursor[i] = excl;
      if (i == n - 1) row_start[n] = excl + d[j];
      excl += d[j];
    }
  }
}

__global__ __launch_bounds__(256) void k_fill(
    const int* __restrict__ dsts, const int* __restrict__ srcs,
    const float* __restrict__ ea, int* cursor,
    int* __restrict__ src_s, float4* __restrict__ ea_s, int ne) {
  int e = blockIdx.x * 256 + threadIdx.x;
  if (e < ne) {
    int p = atomicAdd(&cursor[dsts[e]], 1);
    src_s[p] = srcs[e];
    ea_s[p] = make_float4(ea[(size_t)e * 3], ea[(size_t)e * 3 + 1],
                          ea[(size_t)e * 3 + 2], 0.0f);
  }
}

// ---------------- aggregate with on-the-fly BN (inline finalize) + relu ----------------
template <int BN>
__global__ __launch_bounds__(256) void k_aggregate(
    const bfb* __restrict__ zin, const float4* __restrict__ ea_s,
    const int* __restrict__ src_s, const int* __restrict__ row_start,
    const float* __restrict__ eW, const float* __restrict__ eb,
    const float* __restrict__ sums, const float* __restrict__ gamma,
    const float* __restrict__ beta, float inv_n,
    bfb* __restrict__ zout, int n_nodes) {
  __shared__ float sw0[HID], sw1[HID], sw2[HID], sb[HID], ssc[HID], ssh[HID];
  int tid = threadIdx.x;
  sw0[tid] = eW[tid];
  sw1[tid] = eW[HID + tid];
  sw2[tid] = eW[2 * HID + tid];
  sb[tid] = eb[tid];
  if (BN) {
    float mu = sums[tid] * inv_n;
    float var = sums[HID + tid] * inv_n - mu * mu;
    float sc = gamma[tid] * rsqrtf(var + 1e-5f);
    ssc[tid] = sc;
    ssh[tid] = beta[tid] - mu * sc;
  }
  __syncthreads();
  int w = tid >> 6, lane = tid & 63;
  int n = blockIdx.x * 4 + w;
  if (n >= n_nodes) return;
  int c0 = lane * 4;
  float w0[4], w1[4], w2[4], bb[4], sc[4], sh[4];
#pragma unroll
  for (int j = 0; j < 4; j++) {
    w0[j] = sw0[c0 + j]; w1[j] = sw1[c0 + j]; w2[j] = sw2[c0 + j]; bb[j] = sb[c0 + j];
    if (BN) { sc[j] = ssc[c0 + j]; sh[j] = ssh[c0 + j]; }
  }
  int i = row_start[n], i1 = row_start[n + 1];
  ushort4 hv = *(const ushort4*)&zin[(size_t)n * HID + c0];
  float hvf[4] = {bfb2f(hv.x), bfb2f(hv.y), bfb2f(hv.z), bfb2f(hv.w)};
  float acc[4];
#pragma unroll
  for (int j = 0; j < 4; j++)
    acc[j] = BN ? fmaxf(fmaf(hvf[j], sc[j], sh[j]), 0.0f) : hvf[j];
  for (; i + 2 <= i1; i += 2) {
    int s0 = src_s[i], s1 = src_s[i + 1];
    float4 a0 = ea_s[i];
    float4 a1 = ea_s[i + 1];
    ushort4 sv0 = *(const ushort4*)&zin[(size_t)s0 * HID + c0];
    ushort4 sv1 = *(const ushort4*)&zin[(size_t)s1 * HID + c0];
    float h0[4] = {bfb2f(sv0.x), bfb2f(sv0.y), bfb2f(sv0.z), bfb2f(sv0.w)};
    float h1[4] = {bfb2f(sv1.x), bfb2f(sv1.y), bfb2f(sv1.z), bfb2f(sv1.w)};
#pragma unroll
    for (int j = 0; j < 4; j++) {
      float e0 = fmaf(a0.x, w0[j], fmaf(a0.y, w1[j], fmaf(a0.z, w2[j], bb[j])));
      float e1 = fmaf(a1.x, w0[j], fmaf(a1.y, w1[j], fmaf(a1.z, w2[j], bb[j])));
      float g0 = BN ? fmaxf(fmaf(h0[j], sc[j], sh[j]), 0.0f) : h0[j];
      float g1 = BN ? fmaxf(fmaf(h1[j], sc[j], sh[j]), 0.0f) : h1[j];
      acc[j] += fmaxf(g0 + e0, 0.0f);
      acc[j] += fmaxf(g1 + e1, 0.0f);
    }
  }
  if (i < i1) {
    int s0 = src_s[i];
    float4 a0 = ea_s[i];
    ushort4 sv0 = *(const ushort4*)&zin[(size_t)s0 * HID + c0];
    float h0[4] = {bfb2f(sv0.x), bfb2f(sv0.y), bfb2f(sv0.z), bfb2f(sv0.w)};
#pragma unroll
    for (int j = 0; j < 4; j++) {
      float e0 = fmaf(a0.x, w0[j], fmaf(a0.y, w1[j], fmaf(a0.z, w2[j], bb[j])));
      float g0 = BN ? fmaxf(fmaf(h0[j], sc[j], sh[j]), 0.0f) : h0[j];
      acc[j] += fmaxf(g0 + e0, 0.0f);
    }
  }
  ushort4 o;
  o.x = f2bfb(acc[0]); o.y = f2bfb(acc[1]); o.z = f2bfb(acc[2]); o.w = f2bfb(acc[3]);
  *(ushort4*)&zout[(size_t)n * HID + c0] = o;
}

// ---------------- fused MLP (k_mlp4): z = relu(A@w1+b1)@w2 + b2, + BN stats ----------------
// (512, 8): force VGPR <= 64 -> 8 waves/SIMD (occupancy cliff at 64 per m69).
__global__ __launch_bounds__(512, 8) void k_mlp4(
    const bfb* __restrict__ A, const bfb* __restrict__ Wp1,
    const bfb* __restrict__ Wp2, const float* __restrict__ b1,
    const float* __restrict__ b2, bfb* __restrict__ C,
    int Mreal, float* __restrict__ stats) {
  __shared__ __align__(16) bfb smem[16384];  // 32 KB: A, then t, then C bounce
  int tid = threadIdx.x;
  int lane = tid & 63, wid = tid >> 6;
  int l15 = lane & 15, lq = lane >> 4;
  size_t bm = (size_t)blockIdx.x * 64;

  // ---- stage A[64][256] -> LDS (pre-swizzled source, linear dest) ----
#pragma unroll
  for (int p = 0; p < 4; p++) {
    int b = p * 8192 + tid * 16;
    int row = b >> 9;
    int off = b & 511;
    int src = (off ^ ((row & 7) << 4)) >> 1;
    gld16(A + (bm + row) * 256 + src, (char*)smem + b);
  }
  __syncthreads();  // A staged

  f32x4_t acc[4][2] = {};
  const char* As = (const char*)smem;

  // ---- GEMM1: acc = A @ w1 ----
#pragma unroll
  for (int g = 0; g < 8; g++) {
    f16x8_t af[4];
#pragma unroll
    for (int mi = 0; mi < 4; mi++) {
      int row = mi * 16 + l15;
      int kb = g * 64 + lq * 16;
      af[mi] = *(const f16x8_t*)(As + row * 512 + (kb ^ ((row & 7) << 4)));
    }
#pragma unroll
    for (int ni = 0; ni < 2; ni++) {
      f16x8_t wf = *(const f16x8_t*)(
          Wp1 + ((size_t)((wid * 2 + ni) * 8 + g) * 64 + lane) * 8);
#pragma unroll
      for (int mi = 0; mi < 4; mi++)
        acc[mi][ni] = mfma16(af[mi], wf, acc[mi][ni]);
    }
  }
  __syncthreads();  // all A reads done

  // ---- t = relu(acc + b1) -> LDS (same swizzled layout as A) ----
#pragma unroll
  for (int ni = 0; ni < 2; ni++) {
    int col = wid * 32 + ni * 16 + l15;
    float b = b1[col];
#pragma unroll
    for (int mi = 0; mi < 4; mi++)
#pragma unroll
      for (int r = 0; r < 4; r++) {
        int row = mi * 16 + lq * 4 + r;
        float v = fmaxf(acc[mi][ni][r] + b, 0.0f);
        int byte = row * 512 + ((col * 2) ^ ((row & 7) << 4));
        *(bfb*)((char*)smem + byte) = f2bfb(v);
        acc[mi][ni][r] = 0.0f;
      }
  }
  __syncthreads();  // t visible

  // ---- GEMM2: acc = t @ w2 ----
#pragma unroll
  for (int g = 0; g < 8; g++) {
    f16x8_t af[4];
#pragma unroll
    for (int mi = 0; mi < 4; mi++) {
      int row = mi * 16 + l15;
      int kb = g * 64 + lq * 16;
      af[mi] = *(const f16x8_t*)(As + row * 512 + (kb ^ ((row & 7) << 4)));
    }
#pragma unroll
    for (int ni = 0; ni < 2; ni++) {
      f16x8_t wf = *(const f16x8_t*)(
          Wp2 + ((size_t)((wid * 2 + ni) * 8 + g) * 64 + lane) * 8);
#pragma unroll
      for (int mi = 0; mi < 4; mi++)
        acc[mi][ni] = mfma16(af[mi], wf, acc[mi][ni]);
    }
  }
  __syncthreads();  // t reads done; reuse smem as C bounce

  // ---- epilogue: z = acc + b2 ; BN stats ; bounce ; coalesced out ----
  char* Cs = (char*)smem;
  int crow0 = lq * 4;
  int ccol0 = wid * 32 + l15;
  float ssum[2] = {}, ssq[2] = {};
#pragma unroll
  for (int ni = 0; ni < 2; ni++) {
    int col = ccol0 + ni * 16;
    float b = b2[col];
#pragma unroll
    for (int mi = 0; mi < 4; mi++) {
#pragma unroll
      for (int r = 0; r < 4; r++) {
        int row = mi * 16 + crow0 + r;
        float v = acc[mi][ni][r] + b;
        int byte = (row * 512 + col * 2) ^ ((row & 15) << 4);
        *(bfb*)(Cs + byte) = f2bfb(v);
        if ((int)bm + row < Mreal) {
          ssum[ni] += v;
          ssq[ni] = fmaf(v, v, ssq[ni]);
        }
      }
    }
  }
#pragma unroll
  for (int ni = 0; ni < 2; ni++) {
    float s = ssum[ni], q = ssq[ni];
    s += __shfl_xor(s, 16); s += __shfl_xor(s, 32);
    q += __shfl_xor(q, 16); q += __shfl_xor(q, 32);
    if (lq == 0) {
      int col = ccol0 + ni * 16;
      atomicAdd(&stats[col], s);
      atomicAdd(&stats[HID + col], q);
    }
  }
  __syncthreads();
  {
    char* Cg = (char*)(C + bm * 256);
#pragma unroll
    for (int j = 0; j < 4; j++) {
      int b = j * 8192 + tid * 16;
      int row = b >> 9;
      int off = b & 511;
      float4 v = *(const float4*)(Cs + (row << 9) + (off ^ ((row & 15) << 4)));
      *(float4*)(Cg + b) = v;
    }
  }
}

// ---------------- pool (inline BN finalize + relu on the fly) + divide ----------------
__global__ __launch_bounds__(256) void k_pool(
    const bfb* __restrict__ z, const float* __restrict__ sums,
    const float* __restrict__ gamma, const float* __restrict__ beta, float inv_n,
    const int* __restrict__ batch, float* out, int n_nodes, int npb) {
  int c = threadIdx.x;
  float mu = sums[c] * inv_n;
  float var = sums[HID + c] * inv_n - mu * mu;
  float sc = gamma[c] * rsqrtf(var + 1e-5f);
  float sh = beta[c] - mu * sc;
  int n0 = blockIdx.x * npb;
  int n1 = min(n0 + npb, n_nodes);
  if (n0 >= n1) return;
  int cur = batch[n0];
  float acc = 0.0f;
  for (int n = n0; n < n1; n++) {
    int g = batch[n];
    if (g != cur) {
      atomicAdd(&out[(size_t)cur * HID + c], acc);
      acc = 0.0f;
      cur = g;
    }
    acc += fmaxf(fmaf(ldf(z, (size_t)n * HID + c), sc, sh), 0.0f);
  }
  atomicAdd(&out[(size_t)cur * HID + c], acc);
}

__global__ __launch_bounds__(256) void k_div(
    float* out, const int* __restrict__ batch, int n_nodes) {
  int g = blockIdx.x;
  int lo = 0, hi = n_nodes;
  while (lo < hi) {
    int mid = (lo + hi) >> 1;
    if (batch[mid] < g) lo = mid + 1; else hi = mid;
  }
  int lo2 = lo, hi2 = n_nodes;
  while (lo2 < hi2) {
    int mid = (lo2 + hi2) >> 1;
    if (batch[mid] < g + 1) lo2 = mid + 1; else hi2 = mid;
  }
  float cnt = (float)(lo2 - lo);
  float inv = 1.0f / fmaxf(cnt, 1.0f);
  out[(size_t)g * HID + threadIdx.x] *= inv;
}

extern "C" void kernel_launch(void* const* d_in, const int* in_sizes, int n_in,
                              void* d_out, int out_size, void* d_ws, size_t ws_size,
                              hipStream_t stream) {
  const float* x = (const float*)d_in[0];
  const float* edge_attr = (const float*)d_in[1];
  const int* edge_index = (const int*)d_in[2];
  const int* batch = (const int*)d_in[3];
  const float* in_W = (const float*)d_in[4];
  const float* in_b = (const float*)d_in[5];
  const float* edge_W = (const float*)d_in[6];
  const float* edge_b = (const float*)d_in[7];
  const float* w1 = (const float*)d_in[8];
  const float* b1 = (const float*)d_in[9];
  const float* w2 = (const float*)d_in[10];
  const float* b2 = (const float*)d_in[11];
  const float* gamma = (const float*)d_in[12];
  const float* beta = (const float*)d_in[13];
  float* out = (float*)d_out;

  int n_nodes = in_sizes[3];
  int n_edges = in_sizes[1] / 3;
  int n_graphs = out_size / HID;
  int n_layers = in_sizes[7] / HID;
  float inv_n = 1.0f / (float)n_nodes;

  const int* srcs = edge_index;
  const int* dsts = edge_index + n_edges;

  int Mp = ((n_nodes + 127) / 128) * 128;
  size_t nhp = (size_t)Mp * HID;

  char* ws = (char*)d_ws;
  size_t off = 0;
  float* stats = (float*)(ws + off); off += (size_t)n_layers * 512 * 4;
  bfb* wbuf = (bfb*)(ws + off); off += (size_t)n_layers * 131072 * 2;  // f16 packed
  int* deg = (int*)(ws + off); off += ((size_t)n_nodes * 4 + 255) & ~255ull;
  int* row_start = (int*)(ws + off); off += ((size_t)(n_nodes + 1) * 4 + 255) & ~255ull;
  int* cursor = (int*)(ws + off); off += ((size_t)n_nodes * 4 + 255) & ~255ull;
  int* bsum = (int*)(ws + off); off += 4096;
  int* src_s = (int*)(ws + off); off += ((size_t)n_edges * 4 + 255) & ~255ull;
  float4* ea_s = (float4*)(ws + off); off += (size_t)n_edges * 16;
  bfb* P0 = (bfb*)(ws + off); off += nhp * 2;
  bfb* P1 = (bfb*)(ws + off);

  hipMemsetAsync(out, 0, (size_t)out_size * sizeof(float), stream);
  hipMemsetAsync(deg, 0, (size_t)n_nodes * 4, stream);
  hipMemsetAsync(stats, 0, (size_t)n_layers * 512 * 4, stream);

  k_prep_w<<<(n_layers * 131072 + 255) / 256, 256, 0, stream>>>(w1, w2, wbuf, n_layers);
  k_input_proj<<<(n_nodes + 63) / 64, 256, 0, stream>>>(x, in_W, in_b, P0, n_nodes);

  int np = (n_nodes + 1023) / 1024;
  k_hist<<<(n_edges + 255) / 256, 256, 0, stream>>>(dsts, deg, n_edges);
  k_scan1<<<np, 256, 0, stream>>>(deg, bsum, n_nodes);
  k_scan2<<<1, 256, 0, stream>>>(bsum, np);
  k_scan3<<<np, 256, 0, stream>>>(deg, bsum, row_start, cursor, n_nodes);
  k_fill<<<(n_edges + 255) / 256, 256, 0, stream>>>(dsts, srcs, edge_attr, cursor,
                                                    src_s, ea_s, n_edges);

  bfb* cur = P0;  // raw pre-BN activations of current layer
  bfb* oth = P1;
  int gagg = (n_nodes + 3) / 4;
  int gemm_grid = Mp / 64;
  for (int l = 0; l < n_layers; l++) {
    if (l == 0)
      k_aggregate<0><<<gagg, 256, 0, stream>>>(
          cur, ea_s, src_s, row_start, edge_W + (size_t)l * 3 * HID,
          edge_b + (size_t)l * HID, nullptr, nullptr, nullptr, inv_n, oth, n_nodes);
    else
      k_aggregate<1><<<gagg, 256, 0, stream>>>(
          cur, ea_s, src_s, row_start, edge_W + (size_t)l * 3 * HID,
          edge_b + (size_t)l * HID, stats + (size_t)(l - 1) * 512,
          gamma + (size_t)(l - 1) * HID, beta + (size_t)(l - 1) * HID, inv_n,
          oth, n_nodes);
    bfb* wl = wbuf + (size_t)l * 131072;
    // fused MLP: cur = (relu(oth@w1+b1))@w2 + b2, + BN sums into layer-l stats
    k_mlp4<<<gemm_grid, 512, 0, stream>>>(
        oth, wl, wl + 65536, b1 + (size_t)l * HID, b2 + (size_t)l * HID,
        cur, n_nodes, stats + (size_t)l * 512);
    // cur already holds the new raw z; no swap needed.
  }

  k_pool<<<(n_nodes + 31) / 32, 256, 0, stream>>>(
      cur, stats + (size_t)(n_layers - 1) * 512,
      gamma + (size_t)(n_layers - 1) * HID, beta + (size_t)(n_layers - 1) * HID,
      inv_n, batch, out, n_nodes, 32);
  k_div<<<n_graphs, 256, 0, stream>>>(out, batch, n_nodes);
}

// Round 23
// 961.485 us; speedup vs baseline: 1.6186x; 1.6186x over previous
//
#include <hip/hip_runtime.h>

#define HID 256
typedef unsigned short bfb;  // f16 storage (raw bits)
typedef _Float16 f16x8_t __attribute__((ext_vector_type(8)));
typedef __attribute__((ext_vector_type(4))) float f32x4_t;

// ---------- f16 bit helpers (storage-only; math in fp32) ----------
__device__ inline float bfb2f(bfb u) {
  _Float16 h;
  __builtin_memcpy(&h, &u, 2);
  return (float)h;
}
__device__ inline bfb f2bfb(float f) {
  _Float16 h = (_Float16)f;
  bfb u;
  __builtin_memcpy(&u, &h, 2);
  return u;
}
__device__ inline float ldf(const bfb* p, size_t i) { return bfb2f(p[i]); }
__device__ inline void stf(bfb* p, size_t i, float v) { p[i] = f2bfb(v); }

__device__ inline void gld16(const void* g, void* l) {
  __builtin_amdgcn_global_load_lds(
      (const __attribute__((address_space(1))) void*)g,
      (__attribute__((address_space(3))) void*)l, 16, 0, 0);
}
__device__ inline f32x4_t mfma16(f16x8_t a, f16x8_t b, f32x4_t c) {
  return __builtin_amdgcn_mfma_f32_16x16x32_f16(a, b, c, 0, 0, 0);
}

// ---------------- weight prep: MFMA-fragment-packed f16 ----------------
// dst[e], e = ((ntile*8 + g)*64 + lane)*8 + r  holds W[k][n] with
// n = ntile*16 + (lane&15), k = g*32 + ((lane>>4)&3)*8 + r.
__global__ __launch_bounds__(256) void k_prep_w(
    const float* __restrict__ w1, const float* __restrict__ w2,
    bfb* __restrict__ wbuf, int n_layers) {
  int t = blockIdx.x * 256 + threadIdx.x;
  int total = n_layers * 2 * 65536;
  if (t >= total) return;
  int l = t / 131072;
  int rem = t - l * 131072;
  int which = rem >> 16;
  int e = rem & 65535;
  int r = e & 7;
  int lane = (e >> 3) & 63;
  int g = (e >> 9) & 7;
  int nt = e >> 12;
  int n = nt * 16 + (lane & 15);
  int k = g * 32 + ((lane >> 4) & 3) * 8 + r;
  const float* src = (which ? w2 : w1) + (size_t)l * 65536;
  bfb* dst = wbuf + (size_t)l * 131072 + (size_t)which * 65536;
  dst[e] = f2bfb(src[k * 256 + n]);
}

// ---------------- input projection ----------------
__global__ __launch_bounds__(256) void k_input_proj(
    const float* __restrict__ x, const float* __restrict__ W,
    const float* __restrict__ bias, bfb* __restrict__ z, int n_nodes) {
  __shared__ float sW[14 * HID];
  __shared__ float sx[64 * 14];
  for (int i = threadIdx.x; i < 14 * HID; i += blockDim.x) sW[i] = W[i];
  int c = threadIdx.x;
  float b = bias[c];
  int n0 = blockIdx.x * 64;
  int nmax = min(n0 + 64, n_nodes);
  int cnt = (nmax - n0) * 14;
  for (int i = threadIdx.x; i < cnt; i += blockDim.x) sx[i] = x[(size_t)n0 * 14 + i];
  __syncthreads();
  for (int n = n0; n < nmax; n++) {
    const float* xr = &sx[(n - n0) * 14];
    float acc = b;
#pragma unroll
    for (int k = 0; k < 14; k++) acc = fmaf(xr[k], sW[k * HID + c], acc);
    stf(z, (size_t)n * HID + c, acc);
  }
}

// ---------------- CSR build ----------------
__global__ __launch_bounds__(256) void k_hist(const int* __restrict__ dsts,
                                              int* deg, int ne) {
  int e = blockIdx.x * 256 + threadIdx.x;
  if (e < ne) atomicAdd(&deg[dsts[e]], 1);
}

__global__ __launch_bounds__(256) void k_scan1(const int* __restrict__ deg,
                                               int* bsum, int n) {
  __shared__ int sd[256];
  int i0 = blockIdx.x * 1024 + threadIdx.x * 4;
  int s = 0;
#pragma unroll
  for (int j = 0; j < 4; j++) {
    int i = i0 + j;
    if (i < n) s += deg[i];
  }
  sd[threadIdx.x] = s;
  __syncthreads();
  for (int off = 128; off > 0; off >>= 1) {
    if (threadIdx.x < off) sd[threadIdx.x] += sd[threadIdx.x + off];
    __syncthreads();
  }
  if (threadIdx.x == 0) bsum[blockIdx.x] = sd[0];
}

__global__ __launch_bounds__(256) void k_scan2(int* bsum, int nb) {
  __shared__ int sd[256];
  __shared__ int stot;
  int tid = threadIdx.x;
  int carry = 0;
  for (int base = 0; base < nb; base += 256) {
    int v = (base + tid < nb) ? bsum[base + tid] : 0;
    sd[tid] = v;
    __syncthreads();
    for (int off = 1; off < 256; off <<= 1) {
      int t = (tid >= off) ? sd[tid - off] : 0;
      __syncthreads();
      sd[tid] += t;
      __syncthreads();
    }
    int incl = sd[tid];
    if (base + tid < nb) bsum[base + tid] = carry + incl - v;
    if (tid == 255) stot = incl;
    __syncthreads();
    carry += stot;
    __syncthreads();
  }
}

__global__ __launch_bounds__(256) void k_scan3(const int* __restrict__ deg,
                                               const int* __restrict__ bsum,
                                               int* row_start, int* cursor, int n) {
  __shared__ int sd[256];
  int tid = threadIdx.x;
  int i0 = blockIdx.x * 1024 + tid * 4;
  int d[4];
  int s = 0;
#pragma unroll
  for (int j = 0; j < 4; j++) {
    int i = i0 + j;
    d[j] = (i < n) ? deg[i] : 0;
    s += d[j];
  }
  sd[tid] = s;
  __syncthreads();
  for (int off = 1; off < 256; off <<= 1) {
    int t = (tid >= off) ? sd[tid - off] : 0;
    __syncthreads();
    sd[tid] += t;
    __syncthreads();
  }
  int excl = sd[tid] - s + bsum[blockIdx.x];
#pragma unroll
  for (int j = 0; j < 4; j++) {
    int i = i0 + j;
    if (i < n) {
      row_start[i] = excl;
      cursor[i] = excl;
      if (i == n - 1) row_start[n] = excl + d[j];
      excl += d[j];
    }
  }
}

__global__ __launch_bounds__(256) void k_fill(
    const int* __restrict__ dsts, const int* __restrict__ srcs,
    const float* __restrict__ ea, int* cursor,
    int* __restrict__ src_s, float4* __restrict__ ea_s, int ne) {
  int e = blockIdx.x * 256 + threadIdx.x;
  if (e < ne) {
    int p = atomicAdd(&cursor[dsts[e]], 1);
    src_s[p] = srcs[e];
    ea_s[p] = make_float4(ea[(size_t)e * 3], ea[(size_t)e * 3 + 1],
                          ea[(size_t)e * 3 + 2], 0.0f);
  }
}

// ---------------- aggregate with on-the-fly BN (inline finalize) + relu ----------------
template <int BN>
__global__ __launch_bounds__(256) void k_aggregate(
    const bfb* __restrict__ zin, const float4* __restrict__ ea_s,
    const int* __restrict__ src_s, const int* __restrict__ row_start,
    const float* __restrict__ eW, const float* __restrict__ eb,
    const float* __restrict__ sums, const float* __restrict__ gamma,
    const float* __restrict__ beta, float inv_n,
    bfb* __restrict__ zout, int n_nodes) {
  __shared__ float sw0[HID], sw1[HID], sw2[HID], sb[HID], ssc[HID], ssh[HID];
  int tid = threadIdx.x;
  sw0[tid] = eW[tid];
  sw1[tid] = eW[HID + tid];
  sw2[tid] = eW[2 * HID + tid];
  sb[tid] = eb[tid];
  if (BN) {
    float mu = sums[tid] * inv_n;
    float var = sums[HID + tid] * inv_n - mu * mu;
    float sc = gamma[tid] * rsqrtf(var + 1e-5f);
    ssc[tid] = sc;
    ssh[tid] = beta[tid] - mu * sc;
  }
  __syncthreads();
  int w = tid >> 6, lane = tid & 63;
  int n = blockIdx.x * 4 + w;
  if (n >= n_nodes) return;
  int c0 = lane * 4;
  float w0[4], w1[4], w2[4], bb[4], sc[4], sh[4];
#pragma unroll
  for (int j = 0; j < 4; j++) {
    w0[j] = sw0[c0 + j]; w1[j] = sw1[c0 + j]; w2[j] = sw2[c0 + j]; bb[j] = sb[c0 + j];
    if (BN) { sc[j] = ssc[c0 + j]; sh[j] = ssh[c0 + j]; }
  }
  int i = row_start[n], i1 = row_start[n + 1];
  ushort4 hv = *(const ushort4*)&zin[(size_t)n * HID + c0];
  float hvf[4] = {bfb2f(hv.x), bfb2f(hv.y), bfb2f(hv.z), bfb2f(hv.w)};
  float acc[4];
#pragma unroll
  for (int j = 0; j < 4; j++)
    acc[j] = BN ? fmaxf(fmaf(hvf[j], sc[j], sh[j]), 0.0f) : hvf[j];
  for (; i + 2 <= i1; i += 2) {
    int s0 = src_s[i], s1 = src_s[i + 1];
    float4 a0 = ea_s[i];
    float4 a1 = ea_s[i + 1];
    ushort4 sv0 = *(const ushort4*)&zin[(size_t)s0 * HID + c0];
    ushort4 sv1 = *(const ushort4*)&zin[(size_t)s1 * HID + c0];
    float h0[4] = {bfb2f(sv0.x), bfb2f(sv0.y), bfb2f(sv0.z), bfb2f(sv0.w)};
    float h1[4] = {bfb2f(sv1.x), bfb2f(sv1.y), bfb2f(sv1.z), bfb2f(sv1.w)};
#pragma unroll
    for (int j = 0; j < 4; j++) {
      float e0 = fmaf(a0.x, w0[j], fmaf(a0.y, w1[j], fmaf(a0.z, w2[j], bb[j])));
      float e1 = fmaf(a1.x, w0[j], fmaf(a1.y, w1[j], fmaf(a1.z, w2[j], bb[j])));
      float g0 = BN ? fmaxf(fmaf(h0[j], sc[j], sh[j]), 0.0f) : h0[j];
      float g1 = BN ? fmaxf(fmaf(h1[j], sc[j], sh[j]), 0.0f) : h1[j];
      acc[j] += fmaxf(g0 + e0, 0.0f);
      acc[j] += fmaxf(g1 + e1, 0.0f);
    }
  }
  if (i < i1) {
    int s0 = src_s[i];
    float4 a0 = ea_s[i];
    ushort4 sv0 = *(const ushort4*)&zin[(size_t)s0 * HID + c0];
    float h0[4] = {bfb2f(sv0.x), bfb2f(sv0.y), bfb2f(sv0.z), bfb2f(sv0.w)};
#pragma unroll
    for (int j = 0; j < 4; j++) {
      float e0 = fmaf(a0.x, w0[j], fmaf(a0.y, w1[j], fmaf(a0.z, w2[j], bb[j])));
      float g0 = BN ? fmaxf(fmaf(h0[j], sc[j], sh[j]), 0.0f) : h0[j];
      acc[j] += fmaxf(g0 + e0, 0.0f);
    }
  }
  ushort4 o;
  o.x = f2bfb(acc[0]); o.y = f2bfb(acc[1]); o.z = f2bfb(acc[2]); o.w = f2bfb(acc[3]);
  *(ushort4*)&zout[(size_t)n * HID + c0] = o;
}

// ---------------- fused MLP (k_mlp4): z = relu(A@w1+b1)@w2 + b2, + BN stats ----------------
// (512, 4): cap VGPR at 64 (kernel needs ~62 live; compiler hit 60 in v6) ->
// 4 waves/SIMD = 2 blocks/CU (vs 1 at 68 VGPR). Guardrail: WRITE>110MB = spill.
__global__ __launch_bounds__(512, 4) void k_mlp4(
    const bfb* __restrict__ A, const bfb* __restrict__ Wp1,
    const bfb* __restrict__ Wp2, const float* __restrict__ b1,
    const float* __restrict__ b2, bfb* __restrict__ C,
    int Mreal, float* __restrict__ stats) {
  __shared__ __align__(16) bfb smem[16384];  // 32 KB: A, then t, then C bounce
  int tid = threadIdx.x;
  int lane = tid & 63, wid = tid >> 6;
  int l15 = lane & 15, lq = lane >> 4;
  size_t bm = (size_t)blockIdx.x * 64;

  // ---- stage A[64][256] -> LDS (pre-swizzled source, linear dest) ----
#pragma unroll
  for (int p = 0; p < 4; p++) {
    int b = p * 8192 + tid * 16;
    int row = b >> 9;
    int off = b & 511;
    int src = (off ^ ((row & 7) << 4)) >> 1;
    gld16(A + (bm + row) * 256 + src, (char*)smem + b);
  }
  __syncthreads();  // A staged

  f32x4_t acc[4][2] = {};
  const char* As = (const char*)smem;

  // ---- GEMM1: acc = A @ w1 ----
#pragma unroll
  for (int g = 0; g < 8; g++) {
    f16x8_t af[4];
#pragma unroll
    for (int mi = 0; mi < 4; mi++) {
      int row = mi * 16 + l15;
      int kb = g * 64 + lq * 16;
      af[mi] = *(const f16x8_t*)(As + row * 512 + (kb ^ ((row & 7) << 4)));
    }
#pragma unroll
    for (int ni = 0; ni < 2; ni++) {
      f16x8_t wf = *(const f16x8_t*)(
          Wp1 + ((size_t)((wid * 2 + ni) * 8 + g) * 64 + lane) * 8);
#pragma unroll
      for (int mi = 0; mi < 4; mi++)
        acc[mi][ni] = mfma16(af[mi], wf, acc[mi][ni]);
    }
  }
  __syncthreads();  // all A reads done

  // ---- t = relu(acc + b1) -> LDS (same swizzled layout as A) ----
#pragma unroll
  for (int ni = 0; ni < 2; ni++) {
    int col = wid * 32 + ni * 16 + l15;
    float b = b1[col];
#pragma unroll
    for (int mi = 0; mi < 4; mi++)
#pragma unroll
      for (int r = 0; r < 4; r++) {
        int row = mi * 16 + lq * 4 + r;
        float v = fmaxf(acc[mi][ni][r] + b, 0.0f);
        int byte = row * 512 + ((col * 2) ^ ((row & 7) << 4));
        *(bfb*)((char*)smem + byte) = f2bfb(v);
        acc[mi][ni][r] = 0.0f;
      }
  }
  __syncthreads();  // t visible

  // ---- GEMM2: acc = t @ w2 ----
#pragma unroll
  for (int g = 0; g < 8; g++) {
    f16x8_t af[4];
#pragma unroll
    for (int mi = 0; mi < 4; mi++) {
      int row = mi * 16 + l15;
      int kb = g * 64 + lq * 16;
      af[mi] = *(const f16x8_t*)(As + row * 512 + (kb ^ ((row & 7) << 4)));
    }
#pragma unroll
    for (int ni = 0; ni < 2; ni++) {
      f16x8_t wf = *(const f16x8_t*)(
          Wp2 + ((size_t)((wid * 2 + ni) * 8 + g) * 64 + lane) * 8);
#pragma unroll
      for (int mi = 0; mi < 4; mi++)
        acc[mi][ni] = mfma16(af[mi], wf, acc[mi][ni]);
    }
  }
  __syncthreads();  // t reads done; reuse smem as C bounce

  // ---- epilogue: z = acc + b2 ; BN stats ; bounce ; coalesced out ----
  char* Cs = (char*)smem;
  int crow0 = lq * 4;
  int ccol0 = wid * 32 + l15;
  float ssum[2] = {}, ssq[2] = {};
#pragma unroll
  for (int ni = 0; ni < 2; ni++) {
    int col = ccol0 + ni * 16;
    float b = b2[col];
#pragma unroll
    for (int mi = 0; mi < 4; mi++) {
#pragma unroll
      for (int r = 0; r < 4; r++) {
        int row = mi * 16 + crow0 + r;
        float v = acc[mi][ni][r] + b;
        int byte = (row * 512 + col * 2) ^ ((row & 15) << 4);
        *(bfb*)(Cs + byte) = f2bfb(v);
        if ((int)bm + row < Mreal) {
          ssum[ni] += v;
          ssq[ni] = fmaf(v, v, ssq[ni]);
        }
      }
    }
  }
#pragma unroll
  for (int ni = 0; ni < 2; ni++) {
    float s = ssum[ni], q = ssq[ni];
    s += __shfl_xor(s, 16); s += __shfl_xor(s, 32);
    q += __shfl_xor(q, 16); q += __shfl_xor(q, 32);
    if (lq == 0) {
      int col = ccol0 + ni * 16;
      atomicAdd(&stats[col], s);
      atomicAdd(&stats[HID + col], q);
    }
  }
  __syncthreads();
  {
    char* Cg = (char*)(C + bm * 256);
#pragma unroll
    for (int j = 0; j < 4; j++) {
      int b = j * 8192 + tid * 16;
      int row = b >> 9;
      int off = b & 511;
      float4 v = *(const float4*)(Cs + (row << 9) + (off ^ ((row & 15) << 4)));
      *(float4*)(Cg + b) = v;
    }
  }
}

// ---------------- pool (inline BN finalize + relu on the fly) + divide ----------------
__global__ __launch_bounds__(256) void k_pool(
    const bfb* __restrict__ z, const float* __restrict__ sums,
    const float* __restrict__ gamma, const float* __restrict__ beta, float inv_n,
    const int* __restrict__ batch, float* out, int n_nodes, int npb) {
  int c = threadIdx.x;
  float mu = sums[c] * inv_n;
  float var = sums[HID + c] * inv_n - mu * mu;
  float sc = gamma[c] * rsqrtf(var + 1e-5f);
  float sh = beta[c] - mu * sc;
  int n0 = blockIdx.x * npb;
  int n1 = min(n0 + npb, n_nodes);
  if (n0 >= n1) return;
  int cur = batch[n0];
  float acc = 0.0f;
  for (int n = n0; n < n1; n++) {
    int g = batch[n];
    if (g != cur) {
      atomicAdd(&out[(size_t)cur * HID + c], acc);
      acc = 0.0f;
      cur = g;
    }
    acc += fmaxf(fmaf(ldf(z, (size_t)n * HID + c), sc, sh), 0.0f);
  }
  atomicAdd(&out[(size_t)cur * HID + c], acc);
}

__global__ __launch_bounds__(256) void k_div(
    float* out, const int* __restrict__ batch, int n_nodes) {
  int g = blockIdx.x;
  int lo = 0, hi = n_nodes;
  while (lo < hi) {
    int mid = (lo + hi) >> 1;
    if (batch[mid] < g) lo = mid + 1; else hi = mid;
  }
  int lo2 = lo, hi2 = n_nodes;
  while (lo2 < hi2) {
    int mid = (lo2 + hi2) >> 1;
    if (batch[mid] < g + 1) lo2 = mid + 1; else hi2 = mid;
  }
  float cnt = (float)(lo2 - lo);
  float inv = 1.0f / fmaxf(cnt, 1.0f);
  out[(size_t)g * HID + threadIdx.x] *= inv;
}

extern "C" void kernel_launch(void* const* d_in, const int* in_sizes, int n_in,
                              void* d_out, int out_size, void* d_ws, size_t ws_size,
                              hipStream_t stream) {
  const float* x = (const float*)d_in[0];
  const float* edge_attr = (const float*)d_in[1];
  const int* edge_index = (const int*)d_in[2];
  const int* batch = (const int*)d_in[3];
  const float* in_W = (const float*)d_in[4];
  const float* in_b = (const float*)d_in[5];
  const float* edge_W = (const float*)d_in[6];
  const float* edge_b = (const float*)d_in[7];
  const float* w1 = (const float*)d_in[8];
  const float* b1 = (const float*)d_in[9];
  const float* w2 = (const float*)d_in[10];
  const float* b2 = (const float*)d_in[11];
  const float* gamma = (const float*)d_in[12];
  const float* beta = (const float*)d_in[13];
  float* out = (float*)d_out;

  int n_nodes = in_sizes[3];
  int n_edges = in_sizes[1] / 3;
  int n_graphs = out_size / HID;
  int n_layers = in_sizes[7] / HID;
  float inv_n = 1.0f / (float)n_nodes;

  const int* srcs = edge_index;
  const int* dsts = edge_index + n_edges;

  int Mp = ((n_nodes + 127) / 128) * 128;
  size_t nhp = (size_t)Mp * HID;

  char* ws = (char*)d_ws;
  size_t off = 0;
  float* stats = (float*)(ws + off); off += (size_t)n_layers * 512 * 4;
  bfb* wbuf = (bfb*)(ws + off); off += (size_t)n_layers * 131072 * 2;  // f16 packed
  int* deg = (int*)(ws + off); off += ((size_t)n_nodes * 4 + 255) & ~255ull;
  int* row_start = (int*)(ws + off); off += ((size_t)(n_nodes + 1) * 4 + 255) & ~255ull;
  int* cursor = (int*)(ws + off); off += ((size_t)n_nodes * 4 + 255) & ~255ull;
  int* bsum = (int*)(ws + off); off += 4096;
  int* src_s = (int*)(ws + off); off += ((size_t)n_edges * 4 + 255) & ~255ull;
  float4* ea_s = (float4*)(ws + off); off += (size_t)n_edges * 16;
  bfb* P0 = (bfb*)(ws + off); off += nhp * 2;
  bfb* P1 = (bfb*)(ws + off);

  hipMemsetAsync(out, 0, (size_t)out_size * sizeof(float), stream);
  hipMemsetAsync(deg, 0, (size_t)n_nodes * 4, stream);
  hipMemsetAsync(stats, 0, (size_t)n_layers * 512 * 4, stream);

  k_prep_w<<<(n_layers * 131072 + 255) / 256, 256, 0, stream>>>(w1, w2, wbuf, n_layers);
  k_input_proj<<<(n_nodes + 63) / 64, 256, 0, stream>>>(x, in_W, in_b, P0, n_nodes);

  int np = (n_nodes + 1023) / 1024;
  k_hist<<<(n_edges + 255) / 256, 256, 0, stream>>>(dsts, deg, n_edges);
  k_scan1<<<np, 256, 0, stream>>>(deg, bsum, n_nodes);
  k_scan2<<<1, 256, 0, stream>>>(bsum, np);
  k_scan3<<<np, 256, 0, stream>>>(deg, bsum, row_start, cursor, n_nodes);
  k_fill<<<(n_edges + 255) / 256, 256, 0, stream>>>(dsts, srcs, edge_attr, cursor,
                                                    src_s, ea_s, n_edges);

  bfb* cur = P0;  // raw pre-BN activations of current layer
  bfb* oth = P1;
  int gagg = (n_nodes + 3) / 4;
  int gemm_grid = Mp / 64;
  for (int l = 0; l < n_layers; l++) {
    if (l == 0)
      k_aggregate<0><<<gagg, 256, 0, stream>>>(
          cur, ea_s, src_s, row_start, edge_W + (size_t)l * 3 * HID,
          edge_b + (size_t)l * HID, nullptr, nullptr, nullptr, inv_n, oth, n_nodes);
    else
      k_aggregate<1><<<gagg, 256, 0, stream>>>(
          cur, ea_s, src_s, row_start, edge_W + (size_t)l * 3 * HID,
          edge_b + (size_t)l * HID, stats + (size_t)(l - 1) * 512,
          gamma + (size_t)(l - 1) * HID, beta + (size_t)(l - 1) * HID, inv_n,
          oth, n_nodes);
    bfb* wl = wbuf + (size_t)l * 131072;
    // fused MLP: cur = (relu(oth@w1+b1))@w2 + b2, + BN sums into layer-l stats
    k_mlp4<<<gemm_grid, 512, 0, stream>>>(
        oth, wl, wl + 65536, b1 + (size_t)l * HID, b2 + (size_t)l * HID,
        cur, n_nodes, stats + (size_t)l * 512);
    // cur already holds the new raw z; no swap needed.
  }

  k_pool<<<(n_nodes + 31) / 32, 256, 0, stream>>>(
      cur, stats + (size_t)(n_layers - 1) * 512,
      gamma + (size_t)(n_layers - 1) * HID, beta + (size_t)(n_layers - 1) * HID,
      inv_n, batch, out, n_nodes, 32);
  k_div<<<n_graphs, 256, 0, stream>>>(out, batch, n_nodes);
}

// Round 24
// 918.543 us; speedup vs baseline: 1.6942x; 1.0468x over previous
//
#include <hip/hip_runtime.h>

#define HID 256
typedef unsigned short bfb;  // f16 storage (raw bits)
typedef _Float16 f16x8_t __attribute__((ext_vector_type(8)));
typedef __attribute__((ext_vector_type(4))) float f32x4_t;

// ---------- f16 bit helpers (storage-only; math in fp32) ----------
__device__ inline float bfb2f(bfb u) {
  _Float16 h;
  __builtin_memcpy(&h, &u, 2);
  return (float)h;
}
__device__ inline bfb f2bfb(float f) {
  _Float16 h = (_Float16)f;
  bfb u;
  __builtin_memcpy(&u, &h, 2);
  return u;
}
__device__ inline float ldf(const bfb* p, size_t i) { return bfb2f(p[i]); }
__device__ inline void stf(bfb* p, size_t i, float v) { p[i] = f2bfb(v); }

__device__ inline void gld16(const void* g, void* l) {
  __builtin_amdgcn_global_load_lds(
      (const __attribute__((address_space(1))) void*)g,
      (__attribute__((address_space(3))) void*)l, 16, 0, 0);
}
__device__ inline f32x4_t mfma16(f16x8_t a, f16x8_t b, f32x4_t c) {
  return __builtin_amdgcn_mfma_f32_16x16x32_f16(a, b, c, 0, 0, 0);
}

// ---------------- weight prep: MFMA-fragment-packed f16 ----------------
__global__ __launch_bounds__(256) void k_prep_w(
    const float* __restrict__ w1, const float* __restrict__ w2,
    bfb* __restrict__ wbuf, int n_layers) {
  int t = blockIdx.x * 256 + threadIdx.x;
  int total = n_layers * 2 * 65536;
  if (t >= total) return;
  int l = t / 131072;
  int rem = t - l * 131072;
  int which = rem >> 16;
  int e = rem & 65535;
  int r = e & 7;
  int lane = (e >> 3) & 63;
  int g = (e >> 9) & 7;
  int nt = e >> 12;
  int n = nt * 16 + (lane & 15);
  int k = g * 32 + ((lane >> 4) & 3) * 8 + r;
  const float* src = (which ? w2 : w1) + (size_t)l * 65536;
  bfb* dst = wbuf + (size_t)l * 131072 + (size_t)which * 65536;
  dst[e] = f2bfb(src[k * 256 + n]);
}

// ---------------- input projection ----------------
__global__ __launch_bounds__(256) void k_input_proj(
    const float* __restrict__ x, const float* __restrict__ W,
    const float* __restrict__ bias, bfb* __restrict__ z, int n_nodes) {
  __shared__ float sW[14 * HID];
  __shared__ float sx[64 * 14];
  for (int i = threadIdx.x; i < 14 * HID; i += blockDim.x) sW[i] = W[i];
  int c = threadIdx.x;
  float b = bias[c];
  int n0 = blockIdx.x * 64;
  int nmax = min(n0 + 64, n_nodes);
  int cnt = (nmax - n0) * 14;
  for (int i = threadIdx.x; i < cnt; i += blockDim.x) sx[i] = x[(size_t)n0 * 14 + i];
  __syncthreads();
  for (int n = n0; n < nmax; n++) {
    const float* xr = &sx[(n - n0) * 14];
    float acc = b;
#pragma unroll
    for (int k = 0; k < 14; k++) acc = fmaf(xr[k], sW[k * HID + c], acc);
    stf(z, (size_t)n * HID + c, acc);
  }
}

// ---------------- CSR build ----------------
__global__ __launch_bounds__(256) void k_hist(const int* __restrict__ dsts,
                                              int* deg, int ne) {
  int e = blockIdx.x * 256 + threadIdx.x;
  if (e < ne) atomicAdd(&deg[dsts[e]], 1);
}

__global__ __launch_bounds__(256) void k_scan1(const int* __restrict__ deg,
                                               int* bsum, int n) {
  __shared__ int sd[256];
  int i0 = blockIdx.x * 1024 + threadIdx.x * 4;
  int s = 0;
#pragma unroll
  for (int j = 0; j < 4; j++) {
    int i = i0 + j;
    if (i < n) s += deg[i];
  }
  sd[threadIdx.x] = s;
  __syncthreads();
  for (int off = 128; off > 0; off >>= 1) {
    if (threadIdx.x < off) sd[threadIdx.x] += sd[threadIdx.x + off];
    __syncthreads();
  }
  if (threadIdx.x == 0) bsum[blockIdx.x] = sd[0];
}

__global__ __launch_bounds__(256) void k_scan2(int* bsum, int nb) {
  __shared__ int sd[256];
  __shared__ int stot;
  int tid = threadIdx.x;
  int carry = 0;
  for (int base = 0; base < nb; base += 256) {
    int v = (base + tid < nb) ? bsum[base + tid] : 0;
    sd[tid] = v;
    __syncthreads();
    for (int off = 1; off < 256; off <<= 1) {
      int t = (tid >= off) ? sd[tid - off] : 0;
      __syncthreads();
      sd[tid] += t;
      __syncthreads();
    }
    int incl = sd[tid];
    if (base + tid < nb) bsum[base + tid] = carry + incl - v;
    if (tid == 255) stot = incl;
    __syncthreads();
    carry += stot;
    __syncthreads();
  }
}

__global__ __launch_bounds__(256) void k_scan3(const int* __restrict__ deg,
                                               const int* __restrict__ bsum,
                                               int* row_start, int* cursor, int n) {
  __shared__ int sd[256];
  int tid = threadIdx.x;
  int i0 = blockIdx.x * 1024 + tid * 4;
  int d[4];
  int s = 0;
#pragma unroll
  for (int j = 0; j < 4; j++) {
    int i = i0 + j;
    d[j] = (i < n) ? deg[i] : 0;
    s += d[j];
  }
  sd[tid] = s;
  __syncthreads();
  for (int off = 1; off < 256; off <<= 1) {
    int t = (tid >= off) ? sd[tid - off] : 0;
    __syncthreads();
    sd[tid] += t;
    __syncthreads();
  }
  int excl = sd[tid] - s + bsum[blockIdx.x];
#pragma unroll
  for (int j = 0; j < 4; j++) {
    int i = i0 + j;
    if (i < n) {
      row_start[i] = excl;
      cursor[i] = excl;
      if (i == n - 1) row_start[n] = excl + d[j];
      excl += d[j];
    }
  }
}

__global__ __launch_bounds__(256) void k_fill(
    const int* __restrict__ dsts, const int* __restrict__ srcs,
    const float* __restrict__ ea, int* cursor,
    int* __restrict__ src_s, float4* __restrict__ ea_s, int ne) {
  int e = blockIdx.x * 256 + threadIdx.x;
  if (e < ne) {
    int p = atomicAdd(&cursor[dsts[e]], 1);
    src_s[p] = srcs[e];
    ea_s[p] = make_float4(ea[(size_t)e * 3], ea[(size_t)e * 3 + 1],
                          ea[(size_t)e * 3 + 2], 0.0f);
  }
}

// ---------------- aggregate: 4 nodes per wave (16/block), inline BN + relu ----------------
template <int BN>
__global__ __launch_bounds__(256) void k_aggregate(
    const bfb* __restrict__ zin, const float4* __restrict__ ea_s,
    const int* __restrict__ src_s, const int* __restrict__ row_start,
    const float* __restrict__ eW, const float* __restrict__ eb,
    const float* __restrict__ sums, const float* __restrict__ gamma,
    const float* __restrict__ beta, float inv_n,
    bfb* __restrict__ zout, int n_nodes) {
  __shared__ float sw0[HID], sw1[HID], sw2[HID], sb[HID], ssc[HID], ssh[HID];
  int tid = threadIdx.x;
  sw0[tid] = eW[tid];
  sw1[tid] = eW[HID + tid];
  sw2[tid] = eW[2 * HID + tid];
  sb[tid] = eb[tid];
  if (BN) {
    float mu = sums[tid] * inv_n;
    float var = sums[HID + tid] * inv_n - mu * mu;
    float sc = gamma[tid] * rsqrtf(var + 1e-5f);
    ssc[tid] = sc;
    ssh[tid] = beta[tid] - mu * sc;
  }
  __syncthreads();
  int w = tid >> 6, lane = tid & 63;
  int c0 = lane * 4;
  float w0[4], w1[4], w2[4], bb[4], sc[4], sh[4];
#pragma unroll
  for (int j = 0; j < 4; j++) {
    w0[j] = sw0[c0 + j]; w1[j] = sw1[c0 + j]; w2[j] = sw2[c0 + j]; bb[j] = sb[c0 + j];
    if (BN) { sc[j] = ssc[c0 + j]; sh[j] = ssh[c0 + j]; }
  }
  int nbase = blockIdx.x * 16 + w * 4;
  for (int nn = 0; nn < 4; nn++) {
    int n = nbase + nn;
    if (n >= n_nodes) break;
    int i = row_start[n], i1 = row_start[n + 1];
    ushort4 hv = *(const ushort4*)&zin[(size_t)n * HID + c0];
    float hvf[4] = {bfb2f(hv.x), bfb2f(hv.y), bfb2f(hv.z), bfb2f(hv.w)};
    float acc[4];
#pragma unroll
    for (int j = 0; j < 4; j++)
      acc[j] = BN ? fmaxf(fmaf(hvf[j], sc[j], sh[j]), 0.0f) : hvf[j];
    for (; i + 2 <= i1; i += 2) {
      int s0 = src_s[i], s1 = src_s[i + 1];
      float4 a0 = ea_s[i];
      float4 a1 = ea_s[i + 1];
      ushort4 sv0 = *(const ushort4*)&zin[(size_t)s0 * HID + c0];
      ushort4 sv1 = *(const ushort4*)&zin[(size_t)s1 * HID + c0];
      float h0[4] = {bfb2f(sv0.x), bfb2f(sv0.y), bfb2f(sv0.z), bfb2f(sv0.w)};
      float h1[4] = {bfb2f(sv1.x), bfb2f(sv1.y), bfb2f(sv1.z), bfb2f(sv1.w)};
#pragma unroll
      for (int j = 0; j < 4; j++) {
        float e0 = fmaf(a0.x, w0[j], fmaf(a0.y, w1[j], fmaf(a0.z, w2[j], bb[j])));
        float e1 = fmaf(a1.x, w0[j], fmaf(a1.y, w1[j], fmaf(a1.z, w2[j], bb[j])));
        float g0 = BN ? fmaxf(fmaf(h0[j], sc[j], sh[j]), 0.0f) : h0[j];
        float g1 = BN ? fmaxf(fmaf(h1[j], sc[j], sh[j]), 0.0f) : h1[j];
        acc[j] += fmaxf(g0 + e0, 0.0f);
        acc[j] += fmaxf(g1 + e1, 0.0f);
      }
    }
    if (i < i1) {
      int s0 = src_s[i];
      float4 a0 = ea_s[i];
      ushort4 sv0 = *(const ushort4*)&zin[(size_t)s0 * HID + c0];
      float h0[4] = {bfb2f(sv0.x), bfb2f(sv0.y), bfb2f(sv0.z), bfb2f(sv0.w)};
#pragma unroll
      for (int j = 0; j < 4; j++) {
        float e0 = fmaf(a0.x, w0[j], fmaf(a0.y, w1[j], fmaf(a0.z, w2[j], bb[j])));
        float g0 = BN ? fmaxf(fmaf(h0[j], sc[j], sh[j]), 0.0f) : h0[j];
        acc[j] += fmaxf(g0 + e0, 0.0f);
      }
    }
    ushort4 o;
    o.x = f2bfb(acc[0]); o.y = f2bfb(acc[1]); o.z = f2bfb(acc[2]); o.w = f2bfb(acc[3]);
    *(ushort4*)&zout[(size_t)n * HID + c0] = o;
  }
}

// ---------------- fused MLP (k_mlp4): z = relu(A@w1+b1)@w2 + b2, + BN stats ----------------
__global__ __launch_bounds__(512, 2) void k_mlp4(
    const bfb* __restrict__ A, const bfb* __restrict__ Wp1,
    const bfb* __restrict__ Wp2, const float* __restrict__ b1,
    const float* __restrict__ b2, bfb* __restrict__ C,
    int Mreal, float* __restrict__ stats) {
  __shared__ __align__(16) bfb smem[16384];  // 32 KB: A, then t, then C bounce
  int tid = threadIdx.x;
  int lane = tid & 63, wid = tid >> 6;
  int l15 = lane & 15, lq = lane >> 4;
  size_t bm = (size_t)blockIdx.x * 64;

  // ---- stage A[64][256] -> LDS (pre-swizzled source, linear dest) ----
#pragma unroll
  for (int p = 0; p < 4; p++) {
    int b = p * 8192 + tid * 16;
    int row = b >> 9;
    int off = b & 511;
    int src = (off ^ ((row & 7) << 4)) >> 1;
    gld16(A + (bm + row) * 256 + src, (char*)smem + b);
  }
  __syncthreads();  // A staged

  f32x4_t acc[4][2] = {};
  const char* As = (const char*)smem;

  // ---- GEMM1: acc = A @ w1 ----
#pragma unroll
  for (int g = 0; g < 8; g++) {
    f16x8_t af[4];
#pragma unroll
    for (int mi = 0; mi < 4; mi++) {
      int row = mi * 16 + l15;
      int kb = g * 64 + lq * 16;
      af[mi] = *(const f16x8_t*)(As + row * 512 + (kb ^ ((row & 7) << 4)));
    }
#pragma unroll
    for (int ni = 0; ni < 2; ni++) {
      f16x8_t wf = *(const f16x8_t*)(
          Wp1 + ((size_t)((wid * 2 + ni) * 8 + g) * 64 + lane) * 8);
#pragma unroll
      for (int mi = 0; mi < 4; mi++)
        acc[mi][ni] = mfma16(af[mi], wf, acc[mi][ni]);
    }
  }
  __syncthreads();  // all A reads done

  // ---- t = relu(acc + b1) -> LDS (same swizzled layout as A) ----
#pragma unroll
  for (int ni = 0; ni < 2; ni++) {
    int col = wid * 32 + ni * 16 + l15;
    float b = b1[col];
#pragma unroll
    for (int mi = 0; mi < 4; mi++)
#pragma unroll
      for (int r = 0; r < 4; r++) {
        int row = mi * 16 + lq * 4 + r;
        float v = fmaxf(acc[mi][ni][r] + b, 0.0f);
        int byte = row * 512 + ((col * 2) ^ ((row & 7) << 4));
        *(bfb*)((char*)smem + byte) = f2bfb(v);
        acc[mi][ni][r] = 0.0f;
      }
  }
  __syncthreads();  // t visible

  // ---- GEMM2: acc = t @ w2 ----
#pragma unroll
  for (int g = 0; g < 8; g++) {
    f16x8_t af[4];
#pragma unroll
    for (int mi = 0; mi < 4; mi++) {
      int row = mi * 16 + l15;
      int kb = g * 64 + lq * 16;
      af[mi] = *(const f16x8_t*)(As + row * 512 + (kb ^ ((row & 7) << 4)));
    }
#pragma unroll
    for (int ni = 0; ni < 2; ni++) {
      f16x8_t wf = *(const f16x8_t*)(
          Wp2 + ((size_t)((wid * 2 + ni) * 8 + g) * 64 + lane) * 8);
#pragma unroll
      for (int mi = 0; mi < 4; mi++)
        acc[mi][ni] = mfma16(af[mi], wf, acc[mi][ni]);
    }
  }
  __syncthreads();  // t reads done; reuse smem as C bounce

  // ---- epilogue: z = acc + b2 ; BN stats ; bounce ; coalesced out ----
  char* Cs = (char*)smem;
  int crow0 = lq * 4;
  int ccol0 = wid * 32 + l15;
  float ssum[2] = {}, ssq[2] = {};
#pragma unroll
  for (int ni = 0; ni < 2; ni++) {
    int col = ccol0 + ni * 16;
    float b = b2[col];
#pragma unroll
    for (int mi = 0; mi < 4; mi++) {
#pragma unroll
      for (int r = 0; r < 4; r++) {
        int row = mi * 16 + crow0 + r;
        float v = acc[mi][ni][r] + b;
        int byte = (row * 512 + col * 2) ^ ((row & 15) << 4);
        *(bfb*)(Cs + byte) = f2bfb(v);
        if ((int)bm + row < Mreal) {
          ssum[ni] += v;
          ssq[ni] = fmaf(v, v, ssq[ni]);
        }
      }
    }
  }
#pragma unroll
  for (int ni = 0; ni < 2; ni++) {
    float s = ssum[ni], q = ssq[ni];
    s += __shfl_xor(s, 16); s += __shfl_xor(s, 32);
    q += __shfl_xor(q, 16); q += __shfl_xor(q, 32);
    if (lq == 0) {
      int col = ccol0 + ni * 16;
      atomicAdd(&stats[col], s);
      atomicAdd(&stats[HID + col], q);
    }
  }
  __syncthreads();
  {
    char* Cg = (char*)(C + bm * 256);
#pragma unroll
    for (int j = 0; j < 4; j++) {
      int b = j * 8192 + tid * 16;
      int row = b >> 9;
      int off = b & 511;
      float4 v = *(const float4*)(Cs + (row << 9) + (off ^ ((row & 15) << 4)));
      *(float4*)(Cg + b) = v;
    }
  }
}

// ---------------- pool (inline BN finalize + relu on the fly) + divide ----------------
__global__ __launch_bounds__(256) void k_pool(
    const bfb* __restrict__ z, const float* __restrict__ sums,
    const float* __restrict__ gamma, const float* __restrict__ beta, float inv_n,
    const int* __restrict__ batch, float* out, int n_nodes, int npb) {
  int c = threadIdx.x;
  float mu = sums[c] * inv_n;
  float var = sums[HID + c] * inv_n - mu * mu;
  float sc = gamma[c] * rsqrtf(var + 1e-5f);
  float sh = beta[c] - mu * sc;
  int n0 = blockIdx.x * npb;
  int n1 = min(n0 + npb, n_nodes);
  if (n0 >= n1) return;
  int cur = batch[n0];
  float acc = 0.0f;
  for (int n = n0; n < n1; n++) {
    int g = batch[n];
    if (g != cur) {
      atomicAdd(&out[(size_t)cur * HID + c], acc);
      acc = 0.0f;
      cur = g;
    }
    acc += fmaxf(fmaf(ldf(z, (size_t)n * HID + c), sc, sh), 0.0f);
  }
  atomicAdd(&out[(size_t)cur * HID + c], acc);
}

__global__ __launch_bounds__(256) void k_div(
    float* out, const int* __restrict__ batch, int n_nodes) {
  int g = blockIdx.x;
  int lo = 0, hi = n_nodes;
  while (lo < hi) {
    int mid = (lo + hi) >> 1;
    if (batch[mid] < g) lo = mid + 1; else hi = mid;
  }
  int lo2 = lo, hi2 = n_nodes;
  while (lo2 < hi2) {
    int mid = (lo2 + hi2) >> 1;
    if (batch[mid] < g + 1) lo2 = mid + 1; else hi2 = mid;
  }
  float cnt = (float)(lo2 - lo);
  float inv = 1.0f / fmaxf(cnt, 1.0f);
  out[(size_t)g * HID + threadIdx.x] *= inv;
}

extern "C" void kernel_launch(void* const* d_in, const int* in_sizes, int n_in,
                              void* d_out, int out_size, void* d_ws, size_t ws_size,
                              hipStream_t stream) {
  const float* x = (const float*)d_in[0];
  const float* edge_attr = (const float*)d_in[1];
  const int* edge_index = (const int*)d_in[2];
  const int* batch = (const int*)d_in[3];
  const float* in_W = (const float*)d_in[4];
  const float* in_b = (const float*)d_in[5];
  const float* edge_W = (const float*)d_in[6];
  const float* edge_b = (const float*)d_in[7];
  const float* w1 = (const float*)d_in[8];
  const float* b1 = (const float*)d_in[9];
  const float* w2 = (const float*)d_in[10];
  const float* b2 = (const float*)d_in[11];
  const float* gamma = (const float*)d_in[12];
  const float* beta = (const float*)d_in[13];
  float* out = (float*)d_out;

  int n_nodes = in_sizes[3];
  int n_edges = in_sizes[1] / 3;
  int n_graphs = out_size / HID;
  int n_layers = in_sizes[7] / HID;
  float inv_n = 1.0f / (float)n_nodes;

  const int* srcs = edge_index;
  const int* dsts = edge_index + n_edges;

  int Mp = ((n_nodes + 127) / 128) * 128;
  size_t nhp = (size_t)Mp * HID;

  char* ws = (char*)d_ws;
  size_t off = 0;
  float* stats = (float*)(ws + off); off += (size_t)n_layers * 512 * 4;
  bfb* wbuf = (bfb*)(ws + off); off += (size_t)n_layers * 131072 * 2;  // f16 packed
  int* deg = (int*)(ws + off); off += ((size_t)n_nodes * 4 + 255) & ~255ull;
  int* row_start = (int*)(ws + off); off += ((size_t)(n_nodes + 1) * 4 + 255) & ~255ull;
  int* cursor = (int*)(ws + off); off += ((size_t)n_nodes * 4 + 255) & ~255ull;
  int* bsum = (int*)(ws + off); off += 4096;
  int* src_s = (int*)(ws + off); off += ((size_t)n_edges * 4 + 255) & ~255ull;
  float4* ea_s = (float4*)(ws + off); off += (size_t)n_edges * 16;
  bfb* P0 = (bfb*)(ws + off); off += nhp * 2;
  bfb* P1 = (bfb*)(ws + off);

  hipMemsetAsync(out, 0, (size_t)out_size * sizeof(float), stream);
  hipMemsetAsync(deg, 0, (size_t)n_nodes * 4, stream);
  hipMemsetAsync(stats, 0, (size_t)n_layers * 512 * 4, stream);

  k_prep_w<<<(n_layers * 131072 + 255) / 256, 256, 0, stream>>>(w1, w2, wbuf, n_layers);
  k_input_proj<<<(n_nodes + 63) / 64, 256, 0, stream>>>(x, in_W, in_b, P0, n_nodes);

  int np = (n_nodes + 1023) / 1024;
  k_hist<<<(n_edges + 255) / 256, 256, 0, stream>>>(dsts, deg, n_edges);
  k_scan1<<<np, 256, 0, stream>>>(deg, bsum, n_nodes);
  k_scan2<<<1, 256, 0, stream>>>(bsum, np);
  k_scan3<<<np, 256, 0, stream>>>(deg, bsum, row_start, cursor, n_nodes);
  k_fill<<<(n_edges + 255) / 256, 256, 0, stream>>>(dsts, srcs, edge_attr, cursor,
                                                    src_s, ea_s, n_edges);

  bfb* cur = P0;  // raw pre-BN activations of current layer
  bfb* oth = P1;
  int gagg = (n_nodes + 15) / 16;
  int gemm_grid = Mp / 64;
  for (int l = 0; l < n_layers; l++) {
    if (l == 0)
      k_aggregate<0><<<gagg, 256, 0, stream>>>(
          cur, ea_s, src_s, row_start, edge_W + (size_t)l * 3 * HID,
          edge_b + (size_t)l * HID, nullptr, nullptr, nullptr, inv_n, oth, n_nodes);
    else
      k_aggregate<1><<<gagg, 256, 0, stream>>>(
          cur, ea_s, src_s, row_start, edge_W + (size_t)l * 3 * HID,
          edge_b + (size_t)l * HID, stats + (size_t)(l - 1) * 512,
          gamma + (size_t)(l - 1) * HID, beta + (size_t)(l - 1) * HID, inv_n,
          oth, n_nodes);
    bfb* wl = wbuf + (size_t)l * 131072;
    // fused MLP: cur = (relu(oth@w1+b1))@w2 + b2, + BN sums into layer-l stats
    k_mlp4<<<gemm_grid, 512, 0, stream>>>(
        oth, wl, wl + 65536, b1 + (size_t)l * HID, b2 + (size_t)l * HID,
        cur, n_nodes, stats + (size_t)l * 512);
    // cur already holds the new raw z; no swap needed.
  }

  k_pool<<<(n_nodes + 31) / 32, 256, 0, stream>>>(
      cur, stats + (size_t)(n_layers - 1) * 512,
      gamma + (size_t)(n_layers - 1) * HID, beta + (size_t)(n_layers - 1) * HID,
      inv_n, batch, out, n_nodes, 32);
  k_div<<<n_graphs, 256, 0, stream>>>(out, batch, n_nodes);
}

// Round 25
// 861.263 us; speedup vs baseline: 1.8069x; 1.0665x over previous
//
#include <hip/hip_runtime.h>

#define HID 256
typedef unsigned short bfb;  // f16 storage (raw bits)
typedef _Float16 f16x8_t __attribute__((ext_vector_type(8)));
typedef __attribute__((ext_vector_type(4))) float f32x4_t;

// ---------- f16 bit helpers (storage-only; math in fp32) ----------
__device__ inline float bfb2f(bfb u) {
  _Float16 h;
  __builtin_memcpy(&h, &u, 2);
  return (float)h;
}
__device__ inline bfb f2bfb(float f) {
  _Float16 h = (_Float16)f;
  bfb u;
  __builtin_memcpy(&u, &h, 2);
  return u;
}
__device__ inline float ldf(const bfb* p, size_t i) { return bfb2f(p[i]); }
__device__ inline void stf(bfb* p, size_t i, float v) { p[i] = f2bfb(v); }

__device__ inline void gld16(const void* g, void* l) {
  __builtin_amdgcn_global_load_lds(
      (const __attribute__((address_space(1))) void*)g,
      (__attribute__((address_space(3))) void*)l, 16, 0, 0);
}
__device__ inline f32x4_t mfma16(f16x8_t a, f16x8_t b, f32x4_t c) {
  return __builtin_amdgcn_mfma_f32_16x16x32_f16(a, b, c, 0, 0, 0);
}

// ---------------- weight prep: MFMA-fragment-packed f16 ----------------
__global__ __launch_bounds__(256) void k_prep_w(
    const float* __restrict__ w1, const float* __restrict__ w2,
    bfb* __restrict__ wbuf, int n_layers) {
  int t = blockIdx.x * 256 + threadIdx.x;
  int total = n_layers * 2 * 65536;
  if (t >= total) return;
  int l = t / 131072;
  int rem = t - l * 131072;
  int which = rem >> 16;
  int e = rem & 65535;
  int r = e & 7;
  int lane = (e >> 3) & 63;
  int g = (e >> 9) & 7;
  int nt = e >> 12;
  int n = nt * 16 + (lane & 15);
  int k = g * 32 + ((lane >> 4) & 3) * 8 + r;
  const float* src = (which ? w2 : w1) + (size_t)l * 65536;
  bfb* dst = wbuf + (size_t)l * 131072 + (size_t)which * 65536;
  dst[e] = f2bfb(src[k * 256 + n]);
}

// ---------------- input projection ----------------
__global__ __launch_bounds__(256) void k_input_proj(
    const float* __restrict__ x, const float* __restrict__ W,
    const float* __restrict__ bias, bfb* __restrict__ z, int n_nodes) {
  __shared__ float sW[14 * HID];
  __shared__ float sx[64 * 14];
  for (int i = threadIdx.x; i < 14 * HID; i += blockDim.x) sW[i] = W[i];
  int c = threadIdx.x;
  float b = bias[c];
  int n0 = blockIdx.x * 64;
  int nmax = min(n0 + 64, n_nodes);
  int cnt = (nmax - n0) * 14;
  for (int i = threadIdx.x; i < cnt; i += blockDim.x) sx[i] = x[(size_t)n0 * 14 + i];
  __syncthreads();
  for (int n = n0; n < nmax; n++) {
    const float* xr = &sx[(n - n0) * 14];
    float acc = b;
#pragma unroll
    for (int k = 0; k < 14; k++) acc = fmaf(xr[k], sW[k * HID + c], acc);
    stf(z, (size_t)n * HID + c, acc);
  }
}

// ---------------- CSR build ----------------
__global__ __launch_bounds__(256) void k_hist(const int* __restrict__ dsts,
                                              int* deg, int ne) {
  int e = blockIdx.x * 256 + threadIdx.x;
  if (e < ne) atomicAdd(&deg[dsts[e]], 1);
}

__global__ __launch_bounds__(256) void k_scan1(const int* __restrict__ deg,
                                               int* bsum, int n) {
  __shared__ int sd[256];
  int i0 = blockIdx.x * 1024 + threadIdx.x * 4;
  int s = 0;
#pragma unroll
  for (int j = 0; j < 4; j++) {
    int i = i0 + j;
    if (i < n) s += deg[i];
  }
  sd[threadIdx.x] = s;
  __syncthreads();
  for (int off = 128; off > 0; off >>= 1) {
    if (threadIdx.x < off) sd[threadIdx.x] += sd[threadIdx.x + off];
    __syncthreads();
  }
  if (threadIdx.x == 0) bsum[blockIdx.x] = sd[0];
}

__global__ __launch_bounds__(256) void k_scan2(int* bsum, int nb) {
  __shared__ int sd[256];
  __shared__ int stot;
  int tid = threadIdx.x;
  int carry = 0;
  for (int base = 0; base < nb; base += 256) {
    int v = (base + tid < nb) ? bsum[base + tid] : 0;
    sd[tid] = v;
    __syncthreads();
    for (int off = 1; off < 256; off <<= 1) {
      int t = (tid >= off) ? sd[tid - off] : 0;
      __syncthreads();
      sd[tid] += t;
      __syncthreads();
    }
    int incl = sd[tid];
    if (base + tid < nb) bsum[base + tid] = carry + incl - v;
    if (tid == 255) stot = incl;
    __syncthreads();
    carry += stot;
    __syncthreads();
  }
}

__global__ __launch_bounds__(256) void k_scan3(const int* __restrict__ deg,
                                               const int* __restrict__ bsum,
                                               int* row_start, int* cursor, int n) {
  __shared__ int sd[256];
  int tid = threadIdx.x;
  int i0 = blockIdx.x * 1024 + tid * 4;
  int d[4];
  int s = 0;
#pragma unroll
  for (int j = 0; j < 4; j++) {
    int i = i0 + j;
    d[j] = (i < n) ? deg[i] : 0;
    s += d[j];
  }
  sd[tid] = s;
  __syncthreads();
  for (int off = 1; off < 256; off <<= 1) {
    int t = (tid >= off) ? sd[tid - off] : 0;
    __syncthreads();
    sd[tid] += t;
    __syncthreads();
  }
  int excl = sd[tid] - s + bsum[blockIdx.x];
#pragma unroll
  for (int j = 0; j < 4; j++) {
    int i = i0 + j;
    if (i < n) {
      row_start[i] = excl;
      cursor[i] = excl;
      if (i == n - 1) row_start[n] = excl + d[j];
      excl += d[j];
    }
  }
}

__global__ __launch_bounds__(256) void k_fill(
    const int* __restrict__ dsts, const int* __restrict__ srcs,
    const float* __restrict__ ea, int* cursor,
    int* __restrict__ src_s, float4* __restrict__ ea_s, int ne) {
  int e = blockIdx.x * 256 + threadIdx.x;
  if (e < ne) {
    int p = atomicAdd(&cursor[dsts[e]], 1);
    src_s[p] = srcs[e];
    ea_s[p] = make_float4(ea[(size_t)e * 3], ea[(size_t)e * 3 + 1],
                          ea[(size_t)e * 3 + 2], 0.0f);
  }
}

// ---------------- aggregate: 4 nodes per wave (16/block), inline BN + relu ----------------
template <int BN>
__global__ __launch_bounds__(256) void k_aggregate(
    const bfb* __restrict__ zin, const float4* __restrict__ ea_s,
    const int* __restrict__ src_s, const int* __restrict__ row_start,
    const float* __restrict__ eW, const float* __restrict__ eb,
    const float* __restrict__ sums, const float* __restrict__ gamma,
    const float* __restrict__ beta, float inv_n,
    bfb* __restrict__ zout, int n_nodes) {
  __shared__ float sw0[HID], sw1[HID], sw2[HID], sb[HID], ssc[HID], ssh[HID];
  int tid = threadIdx.x;
  sw0[tid] = eW[tid];
  sw1[tid] = eW[HID + tid];
  sw2[tid] = eW[2 * HID + tid];
  sb[tid] = eb[tid];
  if (BN) {
    float mu = sums[tid] * inv_n;
    float var = sums[HID + tid] * inv_n - mu * mu;
    float sc = gamma[tid] * rsqrtf(var + 1e-5f);
    ssc[tid] = sc;
    ssh[tid] = beta[tid] - mu * sc;
  }
  __syncthreads();
  int w = tid >> 6, lane = tid & 63;
  int c0 = lane * 4;
  float w0[4], w1[4], w2[4], bb[4], sc[4], sh[4];
#pragma unroll
  for (int j = 0; j < 4; j++) {
    w0[j] = sw0[c0 + j]; w1[j] = sw1[c0 + j]; w2[j] = sw2[c0 + j]; bb[j] = sb[c0 + j];
    if (BN) { sc[j] = ssc[c0 + j]; sh[j] = ssh[c0 + j]; }
  }
  int nbase = blockIdx.x * 16 + w * 4;
  for (int nn = 0; nn < 4; nn++) {
    int n = nbase + nn;
    if (n >= n_nodes) break;
    int i = row_start[n], i1 = row_start[n + 1];
    ushort4 hv = *(const ushort4*)&zin[(size_t)n * HID + c0];
    float hvf[4] = {bfb2f(hv.x), bfb2f(hv.y), bfb2f(hv.z), bfb2f(hv.w)};
    float acc[4];
#pragma unroll
    for (int j = 0; j < 4; j++)
      acc[j] = BN ? fmaxf(fmaf(hvf[j], sc[j], sh[j]), 0.0f) : hvf[j];
    for (; i + 2 <= i1; i += 2) {
      int s0 = src_s[i], s1 = src_s[i + 1];
      float4 a0 = ea_s[i];
      float4 a1 = ea_s[i + 1];
      ushort4 sv0 = *(const ushort4*)&zin[(size_t)s0 * HID + c0];
      ushort4 sv1 = *(const ushort4*)&zin[(size_t)s1 * HID + c0];
      float h0[4] = {bfb2f(sv0.x), bfb2f(sv0.y), bfb2f(sv0.z), bfb2f(sv0.w)};
      float h1[4] = {bfb2f(sv1.x), bfb2f(sv1.y), bfb2f(sv1.z), bfb2f(sv1.w)};
#pragma unroll
      for (int j = 0; j < 4; j++) {
        float e0 = fmaf(a0.x, w0[j], fmaf(a0.y, w1[j], fmaf(a0.z, w2[j], bb[j])));
        float e1 = fmaf(a1.x, w0[j], fmaf(a1.y, w1[j], fmaf(a1.z, w2[j], bb[j])));
        float g0 = BN ? fmaxf(fmaf(h0[j], sc[j], sh[j]), 0.0f) : h0[j];
        float g1 = BN ? fmaxf(fmaf(h1[j], sc[j], sh[j]), 0.0f) : h1[j];
        acc[j] += fmaxf(g0 + e0, 0.0f);
        acc[j] += fmaxf(g1 + e1, 0.0f);
      }
    }
    if (i < i1) {
      int s0 = src_s[i];
      float4 a0 = ea_s[i];
      ushort4 sv0 = *(const ushort4*)&zin[(size_t)s0 * HID + c0];
      float h0[4] = {bfb2f(sv0.x), bfb2f(sv0.y), bfb2f(sv0.z), bfb2f(sv0.w)};
#pragma unroll
      for (int j = 0; j < 4; j++) {
        float e0 = fmaf(a0.x, w0[j], fmaf(a0.y, w1[j], fmaf(a0.z, w2[j], bb[j])));
        float g0 = BN ? fmaxf(fmaf(h0[j], sc[j], sh[j]), 0.0f) : h0[j];
        acc[j] += fmaxf(g0 + e0, 0.0f);
      }
    }
    ushort4 o;
    o.x = f2bfb(acc[0]); o.y = f2bfb(acc[1]); o.z = f2bfb(acc[2]); o.w = f2bfb(acc[3]);
    *(ushort4*)&zout[(size_t)n * HID + c0] = o;
  }
}

// ---------------- fused MLP (k_mlp4): 128-row tile, W streamed once per 128 rows ----------------
// 512 threads = 8 waves; wave owns 32 cols x 128 rows. acc[8][2] = 64 VGPR.
// Per g: load wf0/wf1 once, two 64-row halves of A-fragments. 64 KB LDS.
__global__ __launch_bounds__(512, 2) void k_mlp4(
    const bfb* __restrict__ A, const bfb* __restrict__ Wp1,
    const bfb* __restrict__ Wp2, const float* __restrict__ b1,
    const float* __restrict__ b2, bfb* __restrict__ C,
    int Mreal, float* __restrict__ stats) {
  __shared__ __align__(16) bfb smem[32768];  // 64 KB: A, then t, then C bounce
  int tid = threadIdx.x;
  int lane = tid & 63, wid = tid >> 6;
  int l15 = lane & 15, lq = lane >> 4;
  size_t bm = (size_t)blockIdx.x * 128;

  // ---- stage A[128][256] -> LDS (pre-swizzled source, linear dest) ----
#pragma unroll
  for (int p = 0; p < 8; p++) {
    int b = p * 8192 + tid * 16;
    int row = b >> 9;
    int off = b & 511;
    int src = (off ^ ((row & 7) << 4)) >> 1;
    gld16(A + (bm + row) * 256 + src, (char*)smem + b);
  }
  __syncthreads();  // A staged

  f32x4_t acc[8][2] = {};
  const char* As = (const char*)smem;

  // ---- GEMM1: acc = A @ w1 ----
#pragma unroll
  for (int g = 0; g < 8; g++) {
    f16x8_t wf0 = *(const f16x8_t*)(
        Wp1 + ((size_t)((wid * 2 + 0) * 8 + g) * 64 + lane) * 8);
    f16x8_t wf1 = *(const f16x8_t*)(
        Wp1 + ((size_t)((wid * 2 + 1) * 8 + g) * 64 + lane) * 8);
#pragma unroll
    for (int half = 0; half < 2; half++) {
      f16x8_t af[4];
#pragma unroll
      for (int mi = 0; mi < 4; mi++) {
        int row = half * 64 + mi * 16 + l15;
        int kb = g * 64 + lq * 16;
        af[mi] = *(const f16x8_t*)(As + row * 512 + (kb ^ ((row & 7) << 4)));
      }
#pragma unroll
      for (int mi = 0; mi < 4; mi++) {
        acc[half * 4 + mi][0] = mfma16(af[mi], wf0, acc[half * 4 + mi][0]);
        acc[half * 4 + mi][1] = mfma16(af[mi], wf1, acc[half * 4 + mi][1]);
      }
    }
  }
  __syncthreads();  // all A reads done

  // ---- t = relu(acc + b1) -> LDS (same swizzled layout as A) ----
#pragma unroll
  for (int ni = 0; ni < 2; ni++) {
    int col = wid * 32 + ni * 16 + l15;
    float b = b1[col];
#pragma unroll
    for (int a = 0; a < 8; a++)
#pragma unroll
      for (int r = 0; r < 4; r++) {
        int row = (a >> 2) * 64 + (a & 3) * 16 + lq * 4 + r;
        float v = fmaxf(acc[a][ni][r] + b, 0.0f);
        int byte = row * 512 + ((col * 2) ^ ((row & 7) << 4));
        *(bfb*)((char*)smem + byte) = f2bfb(v);
        acc[a][ni][r] = 0.0f;
      }
  }
  __syncthreads();  // t visible

  // ---- GEMM2: acc = t @ w2 ----
#pragma unroll
  for (int g = 0; g < 8; g++) {
    f16x8_t wf0 = *(const f16x8_t*)(
        Wp2 + ((size_t)((wid * 2 + 0) * 8 + g) * 64 + lane) * 8);
    f16x8_t wf1 = *(const f16x8_t*)(
        Wp2 + ((size_t)((wid * 2 + 1) * 8 + g) * 64 + lane) * 8);
#pragma unroll
    for (int half = 0; half < 2; half++) {
      f16x8_t af[4];
#pragma unroll
      for (int mi = 0; mi < 4; mi++) {
        int row = half * 64 + mi * 16 + l15;
        int kb = g * 64 + lq * 16;
        af[mi] = *(const f16x8_t*)(As + row * 512 + (kb ^ ((row & 7) << 4)));
      }
#pragma unroll
      for (int mi = 0; mi < 4; mi++) {
        acc[half * 4 + mi][0] = mfma16(af[mi], wf0, acc[half * 4 + mi][0]);
        acc[half * 4 + mi][1] = mfma16(af[mi], wf1, acc[half * 4 + mi][1]);
      }
    }
  }
  __syncthreads();  // t reads done; reuse smem as C bounce

  // ---- epilogue: z = acc + b2 ; BN stats ; bounce ; coalesced out ----
  char* Cs = (char*)smem;
  int crow0 = lq * 4;
  int ccol0 = wid * 32 + l15;
  float ssum[2] = {}, ssq[2] = {};
#pragma unroll
  for (int ni = 0; ni < 2; ni++) {
    int col = ccol0 + ni * 16;
    float b = b2[col];
#pragma unroll
    for (int a = 0; a < 8; a++) {
#pragma unroll
      for (int r = 0; r < 4; r++) {
        int row = (a >> 2) * 64 + (a & 3) * 16 + crow0 + r;
        float v = acc[a][ni][r] + b;
        int byte = (row * 512 + col * 2) ^ ((row & 15) << 4);
        *(bfb*)(Cs + byte) = f2bfb(v);
        if ((int)bm + row < Mreal) {
          ssum[ni] += v;
          ssq[ni] = fmaf(v, v, ssq[ni]);
        }
      }
    }
  }
#pragma unroll
  for (int ni = 0; ni < 2; ni++) {
    float s = ssum[ni], q = ssq[ni];
    s += __shfl_xor(s, 16); s += __shfl_xor(s, 32);
    q += __shfl_xor(q, 16); q += __shfl_xor(q, 32);
    if (lq == 0) {
      int col = ccol0 + ni * 16;
      atomicAdd(&stats[col], s);
      atomicAdd(&stats[HID + col], q);
    }
  }
  __syncthreads();
  {
    char* Cg = (char*)(C + bm * 256);
#pragma unroll
    for (int j = 0; j < 8; j++) {
      int b = j * 8192 + tid * 16;
      int row = b >> 9;
      int off = b & 511;
      float4 v = *(const float4*)(Cs + (row << 9) + (off ^ ((row & 15) << 4)));
      *(float4*)(Cg + b) = v;
    }
  }
}

// ---------------- pool (inline BN finalize + relu on the fly) + divide ----------------
__global__ __launch_bounds__(256) void k_pool(
    const bfb* __restrict__ z, const float* __restrict__ sums,
    const float* __restrict__ gamma, const float* __restrict__ beta, float inv_n,
    const int* __restrict__ batch, float* out, int n_nodes, int npb) {
  int c = threadIdx.x;
  float mu = sums[c] * inv_n;
  float var = sums[HID + c] * inv_n - mu * mu;
  float sc = gamma[c] * rsqrtf(var + 1e-5f);
  float sh = beta[c] - mu * sc;
  int n0 = blockIdx.x * npb;
  int n1 = min(n0 + npb, n_nodes);
  if (n0 >= n1) return;
  int cur = batch[n0];
  float acc = 0.0f;
  for (int n = n0; n < n1; n++) {
    int g = batch[n];
    if (g != cur) {
      atomicAdd(&out[(size_t)cur * HID + c], acc);
      acc = 0.0f;
      cur = g;
    }
    acc += fmaxf(fmaf(ldf(z, (size_t)n * HID + c), sc, sh), 0.0f);
  }
  atomicAdd(&out[(size_t)cur * HID + c], acc);
}

__global__ __launch_bounds__(256) void k_div(
    float* out, const int* __restrict__ batch, int n_nodes) {
  int g = blockIdx.x;
  int lo = 0, hi = n_nodes;
  while (lo < hi) {
    int mid = (lo + hi) >> 1;
    if (batch[mid] < g) lo = mid + 1; else hi = mid;
  }
  int lo2 = lo, hi2 = n_nodes;
  while (lo2 < hi2) {
    int mid = (lo2 + hi2) >> 1;
    if (batch[mid] < g + 1) lo2 = mid + 1; else hi2 = mid;
  }
  float cnt = (float)(lo2 - lo);
  float inv = 1.0f / fmaxf(cnt, 1.0f);
  out[(size_t)g * HID + threadIdx.x] *= inv;
}

extern "C" void kernel_launch(void* const* d_in, const int* in_sizes, int n_in,
                              void* d_out, int out_size, void* d_ws, size_t ws_size,
                              hipStream_t stream) {
  const float* x = (const float*)d_in[0];
  const float* edge_attr = (const float*)d_in[1];
  const int* edge_index = (const int*)d_in[2];
  const int* batch = (const int*)d_in[3];
  const float* in_W = (const float*)d_in[4];
  const float* in_b = (const float*)d_in[5];
  const float* edge_W = (const float*)d_in[6];
  const float* edge_b = (const float*)d_in[7];
  const float* w1 = (const float*)d_in[8];
  const float* b1 = (const float*)d_in[9];
  const float* w2 = (const float*)d_in[10];
  const float* b2 = (const float*)d_in[11];
  const float* gamma = (const float*)d_in[12];
  const float* beta = (const float*)d_in[13];
  float* out = (float*)d_out;

  int n_nodes = in_sizes[3];
  int n_edges = in_sizes[1] / 3;
  int n_graphs = out_size / HID;
  int n_layers = in_sizes[7] / HID;
  float inv_n = 1.0f / (float)n_nodes;

  const int* srcs = edge_index;
  const int* dsts = edge_index + n_edges;

  int Mp = ((n_nodes + 127) / 128) * 128;
  size_t nhp = (size_t)Mp * HID;

  char* ws = (char*)d_ws;
  size_t off = 0;
  float* stats = (float*)(ws + off); off += (size_t)n_layers * 512 * 4;
  bfb* wbuf = (bfb*)(ws + off); off += (size_t)n_layers * 131072 * 2;  // f16 packed
  int* deg = (int*)(ws + off); off += ((size_t)n_nodes * 4 + 255) & ~255ull;
  int* row_start = (int*)(ws + off); off += ((size_t)(n_nodes + 1) * 4 + 255) & ~255ull;
  int* cursor = (int*)(ws + off); off += ((size_t)n_nodes * 4 + 255) & ~255ull;
  int* bsum = (int*)(ws + off); off += 4096;
  int* src_s = (int*)(ws + off); off += ((size_t)n_edges * 4 + 255) & ~255ull;
  float4* ea_s = (float4*)(ws + off); off += (size_t)n_edges * 16;
  bfb* P0 = (bfb*)(ws + off); off += nhp * 2;
  bfb* P1 = (bfb*)(ws + off);

  hipMemsetAsync(out, 0, (size_t)out_size * sizeof(float), stream);
  hipMemsetAsync(deg, 0, (size_t)n_nodes * 4, stream);
  hipMemsetAsync(stats, 0, (size_t)n_layers * 512 * 4, stream);

  k_prep_w<<<(n_layers * 131072 + 255) / 256, 256, 0, stream>>>(w1, w2, wbuf, n_layers);
  k_input_proj<<<(n_nodes + 63) / 64, 256, 0, stream>>>(x, in_W, in_b, P0, n_nodes);

  int np = (n_nodes + 1023) / 1024;
  k_hist<<<(n_edges + 255) / 256, 256, 0, stream>>>(dsts, deg, n_edges);
  k_scan1<<<np, 256, 0, stream>>>(deg, bsum, n_nodes);
  k_scan2<<<1, 256, 0, stream>>>(bsum, np);
  k_scan3<<<np, 256, 0, stream>>>(deg, bsum, row_start, cursor, n_nodes);
  k_fill<<<(n_edges + 255) / 256, 256, 0, stream>>>(dsts, srcs, edge_attr, cursor,
                                                    src_s, ea_s, n_edges);

  bfb* cur = P0;  // raw pre-BN activations of current layer
  bfb* oth = P1;
  int gagg = (n_nodes + 15) / 16;
  int gemm_grid = Mp / 128;
  for (int l = 0; l < n_layers; l++) {
    if (l == 0)
      k_aggregate<0><<<gagg, 256, 0, stream>>>(
          cur, ea_s, src_s, row_start, edge_W + (size_t)l * 3 * HID,
          edge_b + (size_t)l * HID, nullptr, nullptr, nullptr, inv_n, oth, n_nodes);
    else
      k_aggregate<1><<<gagg, 256, 0, stream>>>(
          cur, ea_s, src_s, row_start, edge_W + (size_t)l * 3 * HID,
          edge_b + (size_t)l * HID, stats + (size_t)(l - 1) * 512,
          gamma + (size_t)(l - 1) * HID, beta + (size_t)(l - 1) * HID, inv_n,
          oth, n_nodes);
    bfb* wl = wbuf + (size_t)l * 131072;
    // fused MLP: cur = (relu(oth@w1+b1))@w2 + b2, + BN sums into layer-l stats
    k_mlp4<<<gemm_grid, 512, 0, stream>>>(
        oth, wl, wl + 65536, b1 + (size_t)l * HID, b2 + (size_t)l * HID,
        cur, n_nodes, stats + (size_t)l * 512);
    // cur already holds the new raw z; no swap needed.
  }

  k_pool<<<(n_nodes + 31) / 32, 256, 0, stream>>>(
      cur, stats + (size_t)(n_layers - 1) * 512,
      gamma + (size_t)(n_layers - 1) * HID, beta + (size_t)(n_layers - 1) * HID,
      inv_n, batch, out, n_nodes, 32);
  k_div<<<n_graphs, 256, 0, stream>>>(out, batch, n_nodes);
}